// Round 10
// baseline (212.981 us; speedup 1.0000x reference)
//
#include <hip/hip_runtime.h>

typedef __attribute__((ext_vector_type(8))) short short8;
typedef __attribute__((ext_vector_type(4))) short short4v;
typedef __attribute__((ext_vector_type(4))) float floatx4;
typedef __attribute__((ext_vector_type(16))) float floatx16;
typedef __attribute__((ext_vector_type(2))) int iv2;

#define GLOBAL_AS __attribute__((address_space(1)))
#define LDS_AS __attribute__((address_space(3)))

__device__ __forceinline__ short f2bs(float f) {
    // RNE float -> bf16 (as short). Inputs finite here.
    union { float f; unsigned u; } v; v.f = f;
    unsigned r = v.u + 0x7fffu + ((v.u >> 16) & 1u);
    return (short)(r >> 16);
}

#if __has_builtin(__builtin_amdgcn_cvt_pk_bf16_f32)
typedef __attribute__((ext_vector_type(2))) __bf16 bf16x2;
__device__ __forceinline__ unsigned pk2(float a, float b) {
    union { bf16x2 v; unsigned u; } u;
    u.v = __builtin_amdgcn_cvt_pk_bf16_f32(a, b);
    return u.u;
}
#else
__device__ __forceinline__ unsigned pk2(float a, float b) {
    // round-half-up, non-negative finite inputs
    union { float f; unsigned u; } x, y; x.f = a; y.f = b;
    return ((y.u + 0x8000u) & 0xffff0000u) | ((x.u + 0x8000u) >> 16);
}
#endif

// ---------------- fused cast fp32 -> bf16 (x + Wq + Wk + Wv) ----------------
__global__ __launch_bounds__(256) void cast_all(const float* __restrict__ x,
                                                const float* __restrict__ Wq,
                                                const float* __restrict__ Wk,
                                                const float* __restrict__ Wv,
                                                short* __restrict__ xb,
                                                short* __restrict__ wb) {
    int b = blockIdx.x;
    int t = threadIdx.x;
    const float* src;
    short* dst;
    int idx;
    if (b < 8192) {
        src = x; dst = xb; idx = b * 1024 + t * 4;
    } else {
        int r = b - 8192;
        int wz = r >> 10;
        src = (wz == 0) ? Wq : (wz == 1) ? Wk : Wv;
        dst = wb + wz * (1 << 20);
        idx = (r & 1023) * 1024 + t * 4;
    }
    float4 v = *(const float4*)(src + idx);
    short4v o;
    o.x = f2bs(v.x); o.y = f2bs(v.y); o.z = f2bs(v.z); o.w = f2bs(v.w);
    *(short4v*)(dst + idx) = o;
}

// ---------------- QKV GEMM v3: R4-proven 128x128 dbuf, counted vmcnt ----------------
__global__ __launch_bounds__(256) void qkv_gemm(const short* __restrict__ xb,
                                                const short* __restrict__ wb,
                                                short* __restrict__ qout,
                                                short* __restrict__ kout,
                                                short* __restrict__ vtout) {
    __shared__ short As[2][128 * 64];  // [m][k], 16B chunks XOR-swizzled: slot = chunk ^ (row&7)
    __shared__ short Bs[2][128 * 64];
    const int K = 1024;
    int tid = threadIdx.x;
    int lane = tid & 63;
    int wid = tid >> 6;
    int quad = lane >> 4;
    int l16 = lane & 15;
    int wm = (wid >> 1) * 64;
    int wn = (wid & 1) * 64;
    int bm = blockIdx.x * 128;
    int bn = blockIdx.y * 128;
    const short* W = wb + (size_t)blockIdx.z * K * 1024;

    floatx4 acc[4][4];
#pragma unroll
    for (int i = 0; i < 4; i++)
#pragma unroll
        for (int j = 0; j < 4; j++) acc[i][j] = (floatx4){0.f, 0.f, 0.f, 0.f};

    int srow = tid >> 3;
    int ssw = ((tid & 7) ^ (srow & 7)) * 8;

#define STAGE_AB(cb, kk) do { \
    _Pragma("unroll") for (int l = 0; l < 4; l++) { \
        const short* g = xb + (size_t)(bm + srow + l * 32) * K + (kk) + ssw; \
        __builtin_amdgcn_global_load_lds((const GLOBAL_AS void*)g, \
            (LDS_AS void*)(&As[cb][0] + tid * 8 + l * 2048), 16, 0, 0); \
    } \
    _Pragma("unroll") for (int l = 0; l < 4; l++) { \
        const short* g = W + (size_t)(bn + srow + l * 32) * K + (kk) + ssw; \
        __builtin_amdgcn_global_load_lds((const GLOBAL_AS void*)g, \
            (LDS_AS void*)(&Bs[cb][0] + tid * 8 + l * 2048), 16, 0, 0); \
    } \
} while (0)

    STAGE_AB(0, 0);

    for (int T = 0; T < 16; T++) {
        int cur = T & 1;
        // WAR guard: all waves done reading buf[cur^1] (step T-1)
        __builtin_amdgcn_sched_barrier(0);
        __builtin_amdgcn_s_barrier();
        __builtin_amdgcn_sched_barrier(0);
        if (T < 15) {
            STAGE_AB(cur ^ 1, (T + 1) * 64);
            asm volatile("s_waitcnt vmcnt(8)" ::: "memory");  // step-T loads (mine) done
        } else {
            asm volatile("s_waitcnt vmcnt(0)" ::: "memory");
        }
        __builtin_amdgcn_sched_barrier(0);
        __builtin_amdgcn_s_barrier();   // step-T LDS visible to all waves
        __builtin_amdgcn_sched_barrier(0);

        const short* Ac = &As[cur][0];
        const short* Bc = &Bs[cur][0];
#pragma unroll
        for (int s = 0; s < 2; s++) {
            int slot = ((s * 4 + quad) ^ (l16 & 7)) * 8;
            short8 af[4], bf[4];
#pragma unroll
            for (int i = 0; i < 4; i++)
                af[i] = *(const short8*)(Ac + (wm + i * 16 + l16) * 64 + slot);
#pragma unroll
            for (int j = 0; j < 4; j++)
                bf[j] = *(const short8*)(Bc + (wn + j * 16 + l16) * 64 + slot);
#pragma unroll
            for (int i = 0; i < 4; i++)
#pragma unroll
                for (int j = 0; j < 4; j++)
                    acc[i][j] = __builtin_amdgcn_mfma_f32_16x16x32_bf16(af[i], bf[j], acc[i][j], 0, 0, 0);
        }
    }
#undef STAGE_AB

    if (blockIdx.z == 2) {
#pragma unroll
        for (int i = 0; i < 4; i++) {
#pragma unroll
            for (int j = 0; j < 4; j++) {
                int m = bm + wm + i * 16 + quad * 4;
                int c = bn + wn + j * 16 + l16;
                int b = m >> 11, nn = m & 2047, h = c >> 6, dd = c & 63;
                short4v pk;
                pk.x = f2bs(acc[i][j][0]);
                pk.y = f2bs(acc[i][j][1]);
                pk.z = f2bs(acc[i][j][2]);
                pk.w = f2bs(acc[i][j][3]);
                *(short4v*)(vtout + ((size_t)(b * 16 + h) * 64 + dd) * 2048 + nn) = pk;
            }
        }
    } else {
        short* dst = (blockIdx.z == 0) ? qout : kout;
        float qs = (blockIdx.z == 0) ? 0.180336881f : 1.0f;  // 0.125*log2(e) folded into Q
#pragma unroll
        for (int i = 0; i < 4; i++) {
#pragma unroll
            for (int j = 0; j < 4; j++) {
#pragma unroll
                for (int r = 0; r < 4; r++) {
                    int m = bm + wm + i * 16 + quad * 4 + r;
                    int c = bn + wn + j * 16 + l16;
                    dst[((size_t)((m >> 11) * 16 + (c >> 6)) * 2048 + (m & 2047)) * 64 + (c & 63)] =
                        f2bs(acc[i][j][r] * qs);
                }
            }
        }
    }
}

// ---------------- Flash attention v5: dual-Q-stream, KVBLK=64, quad-buffered KV ----------------
// vs v3 (R7/R9): KV tiles of 64 keys in 4 LDS slots (4x16KB = 64KB, still 2 blocks/CU).
// With 4 slots the WAR guard is implied (slot staged at t was last read at t-2, and the single
// RAW barrier at t proves all waves passed t-1) -> ONE s_barrier per tile (same total barrier
// count, double the prefetch slack: S(t+2) issued at t, waited at t+2).
// Ledger: prologue S(0),S(1); iter t: vmcnt(4) [S(t) done, S(t+1) in flight] -> barrier ->
// issue S(t+2) -> compute; vmcnt(0) only at t=NT-1. 4 loads/thread per STAGE.
// Streams: A=q-tile qx consumes tiles t<=2qx+1; B=q-tile 15-qx consumes all NT=32-2qx tiles;
// per-block work = 34 half-tiles for every qx (balanced). In-register P via permlane32_swap
// (kb=s>>1, g0=2(s&1) mapping unchanged). 64-elem rows keep the free 8-chunk XOR swizzle.
__global__ __launch_bounds__(256, 2) void attn(const short* __restrict__ q,
                                               const short* __restrict__ k,
                                               const short* __restrict__ vt,
                                               float* __restrict__ out) {
    __shared__ short Ks[4][64 * 64];   // [key][d], 16B slot = chunk ^ (key&7)
    __shared__ short Vs[4][64 * 64];   // [d][key], 16B slot = chunk ^ (d&7)

    int tid = threadIdx.x;
    int lane = tid & 63;
    int wid = tid >> 6;
    int l32 = lane & 31;
    int half = lane >> 5;   // 0/1

    int flat = blockIdx.x;
    int xcd = flat & 7;
    int slot = flat >> 3;            // 0..63
    int bh = xcd * 8 + (slot >> 3);  // 8 (b,h) per XCD
    int qx = slot & 7;
    int b = bh >> 4, h = bh & 15;

    const short* qp = q + (size_t)(b * 16 + h) * 2048 * 64;
    const short* kp = k + (size_t)(b * 16 + h) * 2048 * 64;
    const short* vp = vt + (size_t)(b * 16 + h) * 64 * 2048;

    // staging: 64 rows x 64 elems (128B rows, 8 chunks); 2 ops of 32 rows each for K and V
    int srow = tid >> 3;                      // 0..31
    int ssw = ((tid & 7) ^ (srow & 7)) * 8;   // source-side swizzle; (row&7)==(srow&7) since 32|l*32

#define BARRIER() asm volatile("s_barrier" ::: "memory")
#define STAGE_KV(cb, kvb) do { \
    _Pragma("unroll") for (int l = 0; l < 2; l++) { \
        const short* g = kp + (size_t)((kvb) + srow + l * 32) * 64 + ssw; \
        __builtin_amdgcn_global_load_lds((const GLOBAL_AS void*)g, \
            (LDS_AS void*)(&Ks[cb][0] + tid * 8 + l * 2048), 16, 0, 0); \
    } \
    _Pragma("unroll") for (int l = 0; l < 2; l++) { \
        const short* g = vp + (size_t)(srow + l * 32) * 2048 + (kvb) + ssw; \
        __builtin_amdgcn_global_load_lds((const GLOBAL_AS void*)g, \
            (LDS_AS void*)(&Vs[cb][0] + tid * 8 + l * 2048), 16, 0, 0); \
    } \
} while (0)

// One Q-stream 64-key tile: S^T = K*Q^T, exp2+mask+row-sum, in-reg pack, O += P*V.
#define STREAM_TILE(qf, qlane, oacc, rs, isdiag) do { \
    floatx16 sacc[2]; \
    _Pragma("unroll") for (int kb = 0; kb < 2; kb++) \
    _Pragma("unroll") for (int e = 0; e < 16; e++) sacc[kb][e] = 0.f; \
    __builtin_amdgcn_s_setprio(1); \
    _Pragma("unroll") for (int s = 0; s < 4; s++) { \
        _Pragma("unroll") for (int kb = 0; kb < 2; kb++) { \
            int key = kb * 32 + l32; \
            int c = s * 2 + half; \
            short8 kf = *(const short8*)(Kc + key * 64 + ((c ^ (key & 7)) * 8)); \
            sacc[kb] = __builtin_amdgcn_mfma_f32_32x32x16_bf16(kf, qf[s], sacc[kb], 0, 0, 0); \
        } \
    } \
    __builtin_amdgcn_s_setprio(0); \
    unsigned W0[2][4], W1[2][4]; \
    _Pragma("unroll") for (int kb = 0; kb < 2; kb++) { \
        _Pragma("unroll") for (int e = 0; e < 16; e++) { \
            float p = __builtin_amdgcn_exp2f(sacc[kb][e]); \
            if (isdiag) { \
                int key = kvb + kb * 32 + (e & 3) + 8 * (e >> 2) + 4 * half; \
                p = (key > (qlane)) ? 0.f : p; \
            } \
            sacc[kb][e] = p; \
            rs += p; \
        } \
        _Pragma("unroll") for (int g = 0; g < 4; g++) { \
            W0[kb][g] = pk2(sacc[kb][4 * g + 0], sacc[kb][4 * g + 1]); \
            W1[kb][g] = pk2(sacc[kb][4 * g + 2], sacc[kb][4 * g + 3]); \
        } \
    } \
    __builtin_amdgcn_s_setprio(1); \
    _Pragma("unroll") for (int s = 0; s < 4; s++) { \
        int kb = s >> 1; \
        int g0 = (s & 1) * 2; \
        int g1 = g0 + 1; \
        iv2 r0 = __builtin_amdgcn_permlane32_swap(W0[kb][g0], W0[kb][g1], false, false); \
        iv2 r1 = __builtin_amdgcn_permlane32_swap(W1[kb][g0], W1[kb][g1], false, false); \
        union { int4 v; short8 s8; } pu; \
        pu.v.x = r0.x; pu.v.y = r1.x; pu.v.z = r0.y; pu.v.w = r1.y; \
        short8 pf = pu.s8; \
        _Pragma("unroll") for (int nt = 0; nt < 2; nt++) { \
            int d = nt * 32 + l32; \
            int c = s * 2 + half; \
            short8 vf = *(const short8*)(Vc + d * 64 + ((c ^ (d & 7)) * 8)); \
            oacc[nt] = __builtin_amdgcn_mfma_f32_32x32x16_bf16(pf, vf, oacc[nt], 0, 0, 0); \
        } \
    } \
    __builtin_amdgcn_s_setprio(0); \
} while (0)

#define EPILOG(rs, oacc, qrow_w) do { \
    float tot = (rs) + __shfl_xor((rs), 32); \
    float inv = 1.0f / tot; \
    float invr[16]; \
    _Pragma("unroll") for (int e = 0; e < 16; e++) \
        invr[e] = __shfl(inv, (e & 3) + 8 * (e >> 2) + 4 * half); \
    _Pragma("unroll") for (int nt = 0; nt < 2; nt++) { \
        _Pragma("unroll") for (int e = 0; e < 16; e++) { \
            int r = (e & 3) + 8 * (e >> 2) + 4 * half; \
            int nn = (qrow_w) + r; \
            out[((size_t)b * 2048 + nn) * 1024 + h * 64 + nt * 32 + l32] = oacc[nt][e] * invr[e]; \
        } \
    } \
} while (0)

    int qA = qx;            // stream A: q-tile qx -> consumes 64-key tiles 0..2qA+1
    int qB = 15 - qx;       // stream B: q-tile 15-qx -> consumes all tiles
    int NT = 2 * qB + 2;    // 18..32 staged 64-key tiles
    int lastA = 2 * qA + 1;

    int qrowA = qA * 128 + wid * 32;
    int qrowB = qB * 128 + wid * 32;
    int qlaneA = qrowA + l32;
    int qlaneB = qrowB + l32;

    short8 qfA[4], qfB[4];
#pragma unroll
    for (int s = 0; s < 4; s++) {
        qfA[s] = *(const short8*)(qp + (size_t)qlaneA * 64 + s * 16 + half * 8);
        qfB[s] = *(const short8*)(qp + (size_t)qlaneB * 64 + s * 16 + half * 8);
    }

    floatx16 oaccA[2], oaccB[2];
#pragma unroll
    for (int nt = 0; nt < 2; nt++)
#pragma unroll
        for (int e = 0; e < 16; e++) { oaccA[nt][e] = 0.f; oaccB[nt][e] = 0.f; }
    float rsA = 0.f, rsB = 0.f;

    STAGE_KV(0, 0);
    STAGE_KV(1, 64);

    for (int t = 0; t < NT; t++) {
        int kvb = t * 64;

        if (t + 1 < NT) {
            asm volatile("s_waitcnt vmcnt(4)" ::: "memory");  // S(t) (mine) done; S(t+1) in flight
        } else {
            asm volatile("s_waitcnt vmcnt(0)" ::: "memory");
        }
        BARRIER();   // all waves' S(t) in LDS; all waves past t-1 -> slot (t+2)&3 reusable

        if (t + 2 < NT) STAGE_KV((t + 2) & 3, kvb + 128);

        const short* Kc = &Ks[t & 3][0];
        const short* Vc = &Vs[t & 3][0];

        if (t <= lastA) {
            bool dA = (kvb + 63 > qrowA);
            STREAM_TILE(qfA, qlaneA, oaccA, rsA, dA);
        }
        {
            bool dB = (kvb + 63 > qrowB);
            STREAM_TILE(qfB, qlaneB, oaccB, rsB, dB);
        }
    }

    EPILOG(rsA, oaccA, qrowA);
    EPILOG(rsB, oaccB, qrowB);

#undef STREAM_TILE
#undef EPILOG
#undef STAGE_KV
#undef BARRIER
}

extern "C" void kernel_launch(void* const* d_in, const int* in_sizes, int n_in,
                              void* d_out, int out_size, void* d_ws, size_t ws_size,
                              hipStream_t stream) {
    const float* x = (const float*)d_in[0];
    const float* Wq = (const float*)d_in[1];
    const float* Wk = (const float*)d_in[2];
    const float* Wv = (const float*)d_in[3];
    float* out = (float*)d_out;
    char* ws = (char*)d_ws;

    short* xb = (short*)ws;                          // 16 MB: [8192,1024] bf16
    short* wb = (short*)(ws + (16u << 20));          //  6 MB: [3,1024,1024] bf16
    short* qb = (short*)(ws + (22u << 20));          // 16 MB: [4,16,2048,64]
    short* kb = (short*)(ws + (38u << 20));          // 16 MB: [4,16,2048,64]
    short* vtb = (short*)(ws + (54u << 20));         // 16 MB: [4,16,64,2048]

    cast_all<<<8192 + 3 * 1024, 256, 0, stream>>>(x, Wq, Wk, Wv, xb, wb);
    qkv_gemm<<<dim3(64, 8, 3), 256, 0, stream>>>(xb, wb, qb, kb, vtb);
    attn<<<512, 256, 0, stream>>>(qb, kb, vtb, out);
}

// Round 11
// 210.581 us; speedup vs baseline: 1.0114x; 1.0114x over previous
//
#include <hip/hip_runtime.h>

typedef __attribute__((ext_vector_type(8))) short short8;
typedef __attribute__((ext_vector_type(4))) short short4v;
typedef __attribute__((ext_vector_type(4))) float floatx4;
typedef __attribute__((ext_vector_type(16))) float floatx16;
typedef __attribute__((ext_vector_type(2))) int iv2;

#define GLOBAL_AS __attribute__((address_space(1)))
#define LDS_AS __attribute__((address_space(3)))

__device__ __forceinline__ short f2bs(float f) {
    // RNE float -> bf16 (as short). Inputs finite here.
    union { float f; unsigned u; } v; v.f = f;
    unsigned r = v.u + 0x7fffu + ((v.u >> 16) & 1u);
    return (short)(r >> 16);
}

#if __has_builtin(__builtin_amdgcn_cvt_pk_bf16_f32)
typedef __attribute__((ext_vector_type(2))) __bf16 bf16x2;
__device__ __forceinline__ unsigned pk2(float a, float b) {
    union { bf16x2 v; unsigned u; } u;
    u.v = __builtin_amdgcn_cvt_pk_bf16_f32(a, b);
    return u.u;
}
#else
__device__ __forceinline__ unsigned pk2(float a, float b) {
    // round-half-up, non-negative finite inputs
    union { float f; unsigned u; } x, y; x.f = a; y.f = b;
    return ((y.u + 0x8000u) & 0xffff0000u) | ((x.u + 0x8000u) >> 16);
}
#endif

// ---------------- fused cast fp32 -> bf16 (x + Wq + Wk + Wv) ----------------
__global__ __launch_bounds__(256) void cast_all(const float* __restrict__ x,
                                                const float* __restrict__ Wq,
                                                const float* __restrict__ Wk,
                                                const float* __restrict__ Wv,
                                                short* __restrict__ xb,
                                                short* __restrict__ wb) {
    int b = blockIdx.x;
    int t = threadIdx.x;
    const float* src;
    short* dst;
    int idx;
    if (b < 8192) {
        src = x; dst = xb; idx = b * 1024 + t * 4;
    } else {
        int r = b - 8192;
        int wz = r >> 10;
        src = (wz == 0) ? Wq : (wz == 1) ? Wk : Wv;
        dst = wb + wz * (1 << 20);
        idx = (r & 1023) * 1024 + t * 4;
    }
    float4 v = *(const float4*)(src + idx);
    short4v o;
    o.x = f2bs(v.x); o.y = f2bs(v.y); o.z = f2bs(v.z); o.w = f2bs(v.w);
    *(short4v*)(dst + idx) = o;
}

// ---------------- QKV GEMM v3: R4-proven 128x128 dbuf, counted vmcnt ----------------
__global__ __launch_bounds__(256) void qkv_gemm(const short* __restrict__ xb,
                                                const short* __restrict__ wb,
                                                short* __restrict__ qout,
                                                short* __restrict__ kout,
                                                short* __restrict__ vtout) {
    __shared__ short As[2][128 * 64];  // [m][k], 16B chunks XOR-swizzled: slot = chunk ^ (row&7)
    __shared__ short Bs[2][128 * 64];
    const int K = 1024;
    int tid = threadIdx.x;
    int lane = tid & 63;
    int wid = tid >> 6;
    int quad = lane >> 4;
    int l16 = lane & 15;
    int wm = (wid >> 1) * 64;
    int wn = (wid & 1) * 64;
    int bm = blockIdx.x * 128;
    int bn = blockIdx.y * 128;
    const short* W = wb + (size_t)blockIdx.z * K * 1024;

    floatx4 acc[4][4];
#pragma unroll
    for (int i = 0; i < 4; i++)
#pragma unroll
        for (int j = 0; j < 4; j++) acc[i][j] = (floatx4){0.f, 0.f, 0.f, 0.f};

    int srow = tid >> 3;
    int ssw = ((tid & 7) ^ (srow & 7)) * 8;

#define STAGE_AB(cb, kk) do { \
    _Pragma("unroll") for (int l = 0; l < 4; l++) { \
        const short* g = xb + (size_t)(bm + srow + l * 32) * K + (kk) + ssw; \
        __builtin_amdgcn_global_load_lds((const GLOBAL_AS void*)g, \
            (LDS_AS void*)(&As[cb][0] + tid * 8 + l * 2048), 16, 0, 0); \
    } \
    _Pragma("unroll") for (int l = 0; l < 4; l++) { \
        const short* g = W + (size_t)(bn + srow + l * 32) * K + (kk) + ssw; \
        __builtin_amdgcn_global_load_lds((const GLOBAL_AS void*)g, \
            (LDS_AS void*)(&Bs[cb][0] + tid * 8 + l * 2048), 16, 0, 0); \
    } \
} while (0)

    STAGE_AB(0, 0);

    for (int T = 0; T < 16; T++) {
        int cur = T & 1;
        // WAR guard: all waves done reading buf[cur^1] (step T-1)
        __builtin_amdgcn_sched_barrier(0);
        __builtin_amdgcn_s_barrier();
        __builtin_amdgcn_sched_barrier(0);
        if (T < 15) {
            STAGE_AB(cur ^ 1, (T + 1) * 64);
            asm volatile("s_waitcnt vmcnt(8)" ::: "memory");  // step-T loads (mine) done
        } else {
            asm volatile("s_waitcnt vmcnt(0)" ::: "memory");
        }
        __builtin_amdgcn_sched_barrier(0);
        __builtin_amdgcn_s_barrier();   // step-T LDS visible to all waves
        __builtin_amdgcn_sched_barrier(0);

        const short* Ac = &As[cur][0];
        const short* Bc = &Bs[cur][0];
#pragma unroll
        for (int s = 0; s < 2; s++) {
            int slot = ((s * 4 + quad) ^ (l16 & 7)) * 8;
            short8 af[4], bf[4];
#pragma unroll
            for (int i = 0; i < 4; i++)
                af[i] = *(const short8*)(Ac + (wm + i * 16 + l16) * 64 + slot);
#pragma unroll
            for (int j = 0; j < 4; j++)
                bf[j] = *(const short8*)(Bc + (wn + j * 16 + l16) * 64 + slot);
#pragma unroll
            for (int i = 0; i < 4; i++)
#pragma unroll
                for (int j = 0; j < 4; j++)
                    acc[i][j] = __builtin_amdgcn_mfma_f32_16x16x32_bf16(af[i], bf[j], acc[i][j], 0, 0, 0);
        }
    }
#undef STAGE_AB

    if (blockIdx.z == 2) {
#pragma unroll
        for (int i = 0; i < 4; i++) {
#pragma unroll
            for (int j = 0; j < 4; j++) {
                int m = bm + wm + i * 16 + quad * 4;
                int c = bn + wn + j * 16 + l16;
                int b = m >> 11, nn = m & 2047, h = c >> 6, dd = c & 63;
                short4v pk;
                pk.x = f2bs(acc[i][j][0]);
                pk.y = f2bs(acc[i][j][1]);
                pk.z = f2bs(acc[i][j][2]);
                pk.w = f2bs(acc[i][j][3]);
                *(short4v*)(vtout + ((size_t)(b * 16 + h) * 64 + dd) * 2048 + nn) = pk;
            }
        }
    } else {
        short* dst = (blockIdx.z == 0) ? qout : kout;
        float qs = (blockIdx.z == 0) ? 0.180336881f : 1.0f;  // 0.125*log2(e) folded into Q
#pragma unroll
        for (int i = 0; i < 4; i++) {
#pragma unroll
            for (int j = 0; j < 4; j++) {
#pragma unroll
                for (int r = 0; r < 4; r++) {
                    int m = bm + wm + i * 16 + quad * 4 + r;
                    int c = bn + wn + j * 16 + l16;
                    dst[((size_t)((m >> 11) * 16 + (c >> 6)) * 2048 + (m & 2047)) * 64 + (c & 63)] =
                        f2bs(acc[i][j][r] * qs);
                }
            }
        }
    }
}

// ---------------- Flash attention v6: UNPAIRED q-tiles, 1024 blocks, 4+ waves/SIMD ----------------
// Revised model: MFMA blocks its wave (no intra-wave MFMA||VALU overlap) -> wall time =
// (VALU + MFMA + stalls) overlapped only across co-resident waves. Grid 512 gave exactly
// 2 waves/SIMD (grid-limited). Unpair the (qx,15-qx) fusion: 1024 blocks of ONE 128-row q-tile,
// dbuf KVBLK=64 (LDS 32KB), launch_bounds(256,4) -> 4 blocks/CU = 4 waves/SIMD (2x TLP).
// O/rs are block-local (no-max softmax -> no combine pass). LPT dispatch: qt = 15-(flat>>6)
// (32-tile blocks first); bh = flat&63 keeps XCD = bh%8 -> 8 bh per XCD = 4MB KV = one L2.
// Total compute conserved (272 half-tiles per bh); KV stagings 200->272 per bh (+36% L2, HBM ok).
__global__ __launch_bounds__(256, 4) void attn(const short* __restrict__ q,
                                               const short* __restrict__ k,
                                               const short* __restrict__ vt,
                                               float* __restrict__ out) {
    __shared__ short Ks[2][64 * 64];   // [key][d], 16B slot = chunk ^ (key&7)
    __shared__ short Vs[2][64 * 64];   // [d][key], 16B slot = chunk ^ (d&7)

    int tid = threadIdx.x;
    int lane = tid & 63;
    int wid = tid >> 6;
    int l32 = lane & 31;
    int half = lane >> 5;   // 0/1

    int flat = blockIdx.x;          // 0..1023
    int qt = 15 - (flat >> 6);      // LPT: largest q-tiles dispatch first
    int bh = flat & 63;             // XCD = flat%8 = bh%8 -> per-XCD KV locality
    int b = bh >> 4, h = bh & 15;

    const short* qp = q + (size_t)(b * 16 + h) * 2048 * 64;
    const short* kp = k + (size_t)(b * 16 + h) * 2048 * 64;
    const short* vp = vt + (size_t)(b * 16 + h) * 64 * 2048;

    // staging: 64 rows x 64 elems (128B rows, 8 chunks); 2 ops of 32 rows each for K and V
    int srow = tid >> 3;                      // 0..31
    int ssw = ((tid & 7) ^ (srow & 7)) * 8;   // source-side swizzle

#define BARRIER() asm volatile("s_barrier" ::: "memory")
#define STAGE_KV(cb, kvb) do { \
    _Pragma("unroll") for (int l = 0; l < 2; l++) { \
        const short* g = kp + (size_t)((kvb) + srow + l * 32) * 64 + ssw; \
        __builtin_amdgcn_global_load_lds((const GLOBAL_AS void*)g, \
            (LDS_AS void*)(&Ks[cb][0] + tid * 8 + l * 2048), 16, 0, 0); \
    } \
    _Pragma("unroll") for (int l = 0; l < 2; l++) { \
        const short* g = vp + (size_t)(srow + l * 32) * 2048 + (kvb) + ssw; \
        __builtin_amdgcn_global_load_lds((const GLOBAL_AS void*)g, \
            (LDS_AS void*)(&Vs[cb][0] + tid * 8 + l * 2048), 16, 0, 0); \
    } \
} while (0)

// One 64-key tile: S^T = K*Q^T, exp2+mask+row-sum, in-reg pack, O += P*V.
#define STREAM_TILE(qf, qlane, oacc, rs, isdiag) do { \
    floatx16 sacc[2]; \
    _Pragma("unroll") for (int kb = 0; kb < 2; kb++) \
    _Pragma("unroll") for (int e = 0; e < 16; e++) sacc[kb][e] = 0.f; \
    __builtin_amdgcn_s_setprio(1); \
    _Pragma("unroll") for (int s = 0; s < 4; s++) { \
        _Pragma("unroll") for (int kb = 0; kb < 2; kb++) { \
            int key = kb * 32 + l32; \
            int c = s * 2 + half; \
            short8 kf = *(const short8*)(Kc + key * 64 + ((c ^ (key & 7)) * 8)); \
            sacc[kb] = __builtin_amdgcn_mfma_f32_32x32x16_bf16(kf, qf[s], sacc[kb], 0, 0, 0); \
        } \
    } \
    __builtin_amdgcn_s_setprio(0); \
    unsigned W0[2][4], W1[2][4]; \
    _Pragma("unroll") for (int kb = 0; kb < 2; kb++) { \
        _Pragma("unroll") for (int e = 0; e < 16; e++) { \
            float p = __builtin_amdgcn_exp2f(sacc[kb][e]); \
            if (isdiag) { \
                int key = kvb + kb * 32 + (e & 3) + 8 * (e >> 2) + 4 * half; \
                p = (key > (qlane)) ? 0.f : p; \
            } \
            sacc[kb][e] = p; \
            rs += p; \
        } \
        _Pragma("unroll") for (int g = 0; g < 4; g++) { \
            W0[kb][g] = pk2(sacc[kb][4 * g + 0], sacc[kb][4 * g + 1]); \
            W1[kb][g] = pk2(sacc[kb][4 * g + 2], sacc[kb][4 * g + 3]); \
        } \
    } \
    __builtin_amdgcn_s_setprio(1); \
    _Pragma("unroll") for (int s = 0; s < 4; s++) { \
        int kb = s >> 1; \
        int g0 = (s & 1) * 2; \
        int g1 = g0 + 1; \
        iv2 r0 = __builtin_amdgcn_permlane32_swap(W0[kb][g0], W0[kb][g1], false, false); \
        iv2 r1 = __builtin_amdgcn_permlane32_swap(W1[kb][g0], W1[kb][g1], false, false); \
        union { int4 v; short8 s8; } pu; \
        pu.v.x = r0.x; pu.v.y = r1.x; pu.v.z = r0.y; pu.v.w = r1.y; \
        short8 pf = pu.s8; \
        _Pragma("unroll") for (int nt = 0; nt < 2; nt++) { \
            int d = nt * 32 + l32; \
            int c = s * 2 + half; \
            short8 vf = *(const short8*)(Vc + d * 64 + ((c ^ (d & 7)) * 8)); \
            oacc[nt] = __builtin_amdgcn_mfma_f32_32x32x16_bf16(pf, vf, oacc[nt], 0, 0, 0); \
        } \
    } \
    __builtin_amdgcn_s_setprio(0); \
} while (0)

#define EPILOG(rs, oacc, qrow_w) do { \
    float tot = (rs) + __shfl_xor((rs), 32); \
    float inv = 1.0f / tot; \
    float invr[16]; \
    _Pragma("unroll") for (int e = 0; e < 16; e++) \
        invr[e] = __shfl(inv, (e & 3) + 8 * (e >> 2) + 4 * half); \
    _Pragma("unroll") for (int nt = 0; nt < 2; nt++) { \
        _Pragma("unroll") for (int e = 0; e < 16; e++) { \
            int r = (e & 3) + 8 * (e >> 2) + 4 * half; \
            int nn = (qrow_w) + r; \
            out[((size_t)b * 2048 + nn) * 1024 + h * 64 + nt * 32 + l32] = oacc[nt][e] * invr[e]; \
        } \
    } \
} while (0)

    int NT = 2 * qt + 2;            // 64-key tiles to process (2..32)
    int qrow = qt * 128 + wid * 32; // wave owns q-rows qrow..qrow+31
    int qlane = qrow + l32;

    short8 qf[4];
#pragma unroll
    for (int s = 0; s < 4; s++)
        qf[s] = *(const short8*)(qp + (size_t)qlane * 64 + s * 16 + half * 8);

    floatx16 oacc[2];
#pragma unroll
    for (int nt = 0; nt < 2; nt++)
#pragma unroll
        for (int e = 0; e < 16; e++) oacc[nt][e] = 0.f;
    float rs = 0.f;

    STAGE_KV(0, 0);

    for (int t = 0; t < NT; t++) {
        int kvb = t * 64;

        // WAR guard: all waves done reading slot (t+1)&1 (read at t-1)
        BARRIER();
        if (t + 1 < NT) {
            STAGE_KV((t + 1) & 1, kvb + 64);
            asm volatile("s_waitcnt vmcnt(4)" ::: "memory");  // S(t) (mine) done
        } else {
            asm volatile("s_waitcnt vmcnt(0)" ::: "memory");
        }
        BARRIER();   // RAW: S(t) visible to all waves

        const short* Kc = &Ks[t & 1][0];
        const short* Vc = &Vs[t & 1][0];

        bool d = (kvb + 63 > qrow);
        STREAM_TILE(qf, qlane, oacc, rs, d);
    }

    EPILOG(rs, oacc, qrow);

#undef STREAM_TILE
#undef EPILOG
#undef STAGE_KV
#undef BARRIER
}

extern "C" void kernel_launch(void* const* d_in, const int* in_sizes, int n_in,
                              void* d_out, int out_size, void* d_ws, size_t ws_size,
                              hipStream_t stream) {
    const float* x = (const float*)d_in[0];
    const float* Wq = (const float*)d_in[1];
    const float* Wk = (const float*)d_in[2];
    const float* Wv = (const float*)d_in[3];
    float* out = (float*)d_out;
    char* ws = (char*)d_ws;

    short* xb = (short*)ws;                          // 16 MB: [8192,1024] bf16
    short* wb = (short*)(ws + (16u << 20));          //  6 MB: [3,1024,1024] bf16
    short* qb = (short*)(ws + (22u << 20));          // 16 MB: [4,16,2048,64]
    short* kb = (short*)(ws + (38u << 20));          // 16 MB: [4,16,2048,64]
    short* vtb = (short*)(ws + (54u << 20));         // 16 MB: [4,16,64,2048]

    cast_all<<<8192 + 3 * 1024, 256, 0, stream>>>(x, Wq, Wk, Wv, xb, wb);
    qkv_gemm<<<dim3(64, 8, 3), 256, 0, stream>>>(xb, wb, qb, kb, vtb);
    attn<<<1024, 256, 0, stream>>>(qb, kb, vtb, out);
}

// Round 12
// 207.415 us; speedup vs baseline: 1.0268x; 1.0153x over previous
//
#include <hip/hip_runtime.h>

typedef __attribute__((ext_vector_type(8))) short short8;
typedef __attribute__((ext_vector_type(4))) short short4v;
typedef __attribute__((ext_vector_type(4))) float floatx4;
typedef __attribute__((ext_vector_type(16))) float floatx16;
typedef __attribute__((ext_vector_type(2))) int iv2;

#define GLOBAL_AS __attribute__((address_space(1)))
#define LDS_AS __attribute__((address_space(3)))

__device__ __forceinline__ short f2bs(float f) {
    // RNE float -> bf16 (as short). Inputs finite here.
    union { float f; unsigned u; } v; v.f = f;
    unsigned r = v.u + 0x7fffu + ((v.u >> 16) & 1u);
    return (short)(r >> 16);
}

#if __has_builtin(__builtin_amdgcn_cvt_pk_bf16_f32)
typedef __attribute__((ext_vector_type(2))) __bf16 bf16x2;
__device__ __forceinline__ unsigned pk2(float a, float b) {
    union { bf16x2 v; unsigned u; } u;
    u.v = __builtin_amdgcn_cvt_pk_bf16_f32(a, b);
    return u.u;
}
#else
__device__ __forceinline__ unsigned pk2(float a, float b) {
    // round-half-up, non-negative finite inputs
    union { float f; unsigned u; } x, y; x.f = a; y.f = b;
    return ((y.u + 0x8000u) & 0xffff0000u) | ((x.u + 0x8000u) >> 16);
}
#endif

// ---------------- fused cast fp32 -> bf16 (x + Wq + Wk + Wv) ----------------
__global__ __launch_bounds__(256) void cast_all(const float* __restrict__ x,
                                                const float* __restrict__ Wq,
                                                const float* __restrict__ Wk,
                                                const float* __restrict__ Wv,
                                                short* __restrict__ xb,
                                                short* __restrict__ wb) {
    int b = blockIdx.x;
    int t = threadIdx.x;
    const float* src;
    short* dst;
    int idx;
    if (b < 8192) {
        src = x; dst = xb; idx = b * 1024 + t * 4;
    } else {
        int r = b - 8192;
        int wz = r >> 10;
        src = (wz == 0) ? Wq : (wz == 1) ? Wk : Wv;
        dst = wb + wz * (1 << 20);
        idx = (r & 1023) * 1024 + t * 4;
    }
    float4 v = *(const float4*)(src + idx);
    short4v o;
    o.x = f2bs(v.x); o.y = f2bs(v.y); o.z = f2bs(v.z); o.w = f2bs(v.w);
    *(short4v*)(dst + idx) = o;
}

// ---------------- QKV GEMM v3: R4-proven 128x128 dbuf, counted vmcnt ----------------
__global__ __launch_bounds__(256) void qkv_gemm(const short* __restrict__ xb,
                                                const short* __restrict__ wb,
                                                short* __restrict__ qout,
                                                short* __restrict__ kout,
                                                short* __restrict__ vtout) {
    __shared__ short As[2][128 * 64];  // [m][k], 16B chunks XOR-swizzled: slot = chunk ^ (row&7)
    __shared__ short Bs[2][128 * 64];
    const int K = 1024;
    int tid = threadIdx.x;
    int lane = tid & 63;
    int wid = tid >> 6;
    int quad = lane >> 4;
    int l16 = lane & 15;
    int wm = (wid >> 1) * 64;
    int wn = (wid & 1) * 64;
    int bm = blockIdx.x * 128;
    int bn = blockIdx.y * 128;
    const short* W = wb + (size_t)blockIdx.z * K * 1024;

    floatx4 acc[4][4];
#pragma unroll
    for (int i = 0; i < 4; i++)
#pragma unroll
        for (int j = 0; j < 4; j++) acc[i][j] = (floatx4){0.f, 0.f, 0.f, 0.f};

    int srow = tid >> 3;
    int ssw = ((tid & 7) ^ (srow & 7)) * 8;

#define STAGE_AB(cb, kk) do { \
    _Pragma("unroll") for (int l = 0; l < 4; l++) { \
        const short* g = xb + (size_t)(bm + srow + l * 32) * K + (kk) + ssw; \
        __builtin_amdgcn_global_load_lds((const GLOBAL_AS void*)g, \
            (LDS_AS void*)(&As[cb][0] + tid * 8 + l * 2048), 16, 0, 0); \
    } \
    _Pragma("unroll") for (int l = 0; l < 4; l++) { \
        const short* g = W + (size_t)(bn + srow + l * 32) * K + (kk) + ssw; \
        __builtin_amdgcn_global_load_lds((const GLOBAL_AS void*)g, \
            (LDS_AS void*)(&Bs[cb][0] + tid * 8 + l * 2048), 16, 0, 0); \
    } \
} while (0)

    STAGE_AB(0, 0);

    for (int T = 0; T < 16; T++) {
        int cur = T & 1;
        // WAR guard: all waves done reading buf[cur^1] (step T-1)
        __builtin_amdgcn_sched_barrier(0);
        __builtin_amdgcn_s_barrier();
        __builtin_amdgcn_sched_barrier(0);
        if (T < 15) {
            STAGE_AB(cur ^ 1, (T + 1) * 64);
            asm volatile("s_waitcnt vmcnt(8)" ::: "memory");  // step-T loads (mine) done
        } else {
            asm volatile("s_waitcnt vmcnt(0)" ::: "memory");
        }
        __builtin_amdgcn_sched_barrier(0);
        __builtin_amdgcn_s_barrier();   // step-T LDS visible to all waves
        __builtin_amdgcn_sched_barrier(0);

        const short* Ac = &As[cur][0];
        const short* Bc = &Bs[cur][0];
#pragma unroll
        for (int s = 0; s < 2; s++) {
            int slot = ((s * 4 + quad) ^ (l16 & 7)) * 8;
            short8 af[4], bf[4];
#pragma unroll
            for (int i = 0; i < 4; i++)
                af[i] = *(const short8*)(Ac + (wm + i * 16 + l16) * 64 + slot);
#pragma unroll
            for (int j = 0; j < 4; j++)
                bf[j] = *(const short8*)(Bc + (wn + j * 16 + l16) * 64 + slot);
#pragma unroll
            for (int i = 0; i < 4; i++)
#pragma unroll
                for (int j = 0; j < 4; j++)
                    acc[i][j] = __builtin_amdgcn_mfma_f32_16x16x32_bf16(af[i], bf[j], acc[i][j], 0, 0, 0);
        }
    }
#undef STAGE_AB

    if (blockIdx.z == 2) {
#pragma unroll
        for (int i = 0; i < 4; i++) {
#pragma unroll
            for (int j = 0; j < 4; j++) {
                int m = bm + wm + i * 16 + quad * 4;
                int c = bn + wn + j * 16 + l16;
                int b = m >> 11, nn = m & 2047, h = c >> 6, dd = c & 63;
                short4v pk;
                pk.x = f2bs(acc[i][j][0]);
                pk.y = f2bs(acc[i][j][1]);
                pk.z = f2bs(acc[i][j][2]);
                pk.w = f2bs(acc[i][j][3]);
                *(short4v*)(vtout + ((size_t)(b * 16 + h) * 64 + dd) * 2048 + nn) = pk;
            }
        }
    } else {
        short* dst = (blockIdx.z == 0) ? qout : kout;
        float qs = (blockIdx.z == 0) ? 0.180336881f : 1.0f;  // 0.125*log2(e) folded into Q
#pragma unroll
        for (int i = 0; i < 4; i++) {
#pragma unroll
            for (int j = 0; j < 4; j++) {
#pragma unroll
                for (int r = 0; r < 4; r++) {
                    int m = bm + wm + i * 16 + quad * 4 + r;
                    int c = bn + wn + j * 16 + l16;
                    dst[((size_t)((m >> 11) * 16 + (c >> 6)) * 2048 + (m & 2047)) * 64 + (c & 63)] =
                        f2bs(acc[i][j][r] * qs);
                }
            }
        }
    }
}

// ---------------- Flash attention v6b: unpaired q-tiles + per-CU load-balanced qt map ----------------
// v6 counters: attn < 66us (out of top-5) -> TLP theory confirmed. Remaining defect: with 1024
// blocks at 4/CU (one dispatch round), CU c runs blocks {c, c+256, c+512, c+768} CONCURRENTLY;
// v6's qt=15-(flat>>6) gave per-CU tile loads 80..56 (30% idle on light CUs). Remap so every
// CU's four qt sum to 30 (68 tiles = exact average): r=flat>>8, j=(flat>>6)&3:
//   r0: qt=15-j, r1: 8+j, r2: 7-j, r3: j   (all j-columns sum 30; all 16 qt per bh covered).
// XCD = flat&7 = bh&7 (KV L2 locality) and LPT order (heavy round first) preserved.
__global__ __launch_bounds__(256, 4) void attn(const short* __restrict__ q,
                                               const short* __restrict__ k,
                                               const short* __restrict__ vt,
                                               float* __restrict__ out) {
    __shared__ short Ks[2][64 * 64];   // [key][d], 16B slot = chunk ^ (key&7)
    __shared__ short Vs[2][64 * 64];   // [d][key], 16B slot = chunk ^ (d&7)

    int tid = threadIdx.x;
    int lane = tid & 63;
    int wid = tid >> 6;
    int l32 = lane & 31;
    int half = lane >> 5;   // 0/1

    int flat = blockIdx.x;          // 0..1023
    int r4 = flat >> 8;             // concurrent-round index (same-CU group)
    int j4 = (flat >> 6) & 3;
    int qt = (r4 == 0) ? (15 - j4) : (r4 == 1) ? (8 + j4) : (r4 == 2) ? (7 - j4) : j4;
    int bh = flat & 63;             // XCD = flat%8 = bh%8 -> per-XCD KV locality
    int b = bh >> 4, h = bh & 15;

    const short* qp = q + (size_t)(b * 16 + h) * 2048 * 64;
    const short* kp = k + (size_t)(b * 16 + h) * 2048 * 64;
    const short* vp = vt + (size_t)(b * 16 + h) * 64 * 2048;

    // staging: 64 rows x 64 elems (128B rows, 8 chunks); 2 ops of 32 rows each for K and V
    int srow = tid >> 3;                      // 0..31
    int ssw = ((tid & 7) ^ (srow & 7)) * 8;   // source-side swizzle

#define BARRIER() asm volatile("s_barrier" ::: "memory")
#define STAGE_KV(cb, kvb) do { \
    _Pragma("unroll") for (int l = 0; l < 2; l++) { \
        const short* g = kp + (size_t)((kvb) + srow + l * 32) * 64 + ssw; \
        __builtin_amdgcn_global_load_lds((const GLOBAL_AS void*)g, \
            (LDS_AS void*)(&Ks[cb][0] + tid * 8 + l * 2048), 16, 0, 0); \
    } \
    _Pragma("unroll") for (int l = 0; l < 2; l++) { \
        const short* g = vp + (size_t)(srow + l * 32) * 2048 + (kvb) + ssw; \
        __builtin_amdgcn_global_load_lds((const GLOBAL_AS void*)g, \
            (LDS_AS void*)(&Vs[cb][0] + tid * 8 + l * 2048), 16, 0, 0); \
    } \
} while (0)

// One 64-key tile: S^T = K*Q^T, exp2+mask+row-sum, in-reg pack, O += P*V.
#define STREAM_TILE(qf, qlane, oacc, rs, isdiag) do { \
    floatx16 sacc[2]; \
    _Pragma("unroll") for (int kb = 0; kb < 2; kb++) \
    _Pragma("unroll") for (int e = 0; e < 16; e++) sacc[kb][e] = 0.f; \
    __builtin_amdgcn_s_setprio(1); \
    _Pragma("unroll") for (int s = 0; s < 4; s++) { \
        _Pragma("unroll") for (int kb = 0; kb < 2; kb++) { \
            int key = kb * 32 + l32; \
            int c = s * 2 + half; \
            short8 kf = *(const short8*)(Kc + key * 64 + ((c ^ (key & 7)) * 8)); \
            sacc[kb] = __builtin_amdgcn_mfma_f32_32x32x16_bf16(kf, qf[s], sacc[kb], 0, 0, 0); \
        } \
    } \
    __builtin_amdgcn_s_setprio(0); \
    unsigned W0[2][4], W1[2][4]; \
    _Pragma("unroll") for (int kb = 0; kb < 2; kb++) { \
        _Pragma("unroll") for (int e = 0; e < 16; e++) { \
            float p = __builtin_amdgcn_exp2f(sacc[kb][e]); \
            if (isdiag) { \
                int key = kvb + kb * 32 + (e & 3) + 8 * (e >> 2) + 4 * half; \
                p = (key > (qlane)) ? 0.f : p; \
            } \
            sacc[kb][e] = p; \
            rs += p; \
        } \
        _Pragma("unroll") for (int g = 0; g < 4; g++) { \
            W0[kb][g] = pk2(sacc[kb][4 * g + 0], sacc[kb][4 * g + 1]); \
            W1[kb][g] = pk2(sacc[kb][4 * g + 2], sacc[kb][4 * g + 3]); \
        } \
    } \
    __builtin_amdgcn_s_setprio(1); \
    _Pragma("unroll") for (int s = 0; s < 4; s++) { \
        int kb = s >> 1; \
        int g0 = (s & 1) * 2; \
        int g1 = g0 + 1; \
        iv2 r0 = __builtin_amdgcn_permlane32_swap(W0[kb][g0], W0[kb][g1], false, false); \
        iv2 r1 = __builtin_amdgcn_permlane32_swap(W1[kb][g0], W1[kb][g1], false, false); \
        union { int4 v; short8 s8; } pu; \
        pu.v.x = r0.x; pu.v.y = r1.x; pu.v.z = r0.y; pu.v.w = r1.y; \
        short8 pf = pu.s8; \
        _Pragma("unroll") for (int nt = 0; nt < 2; nt++) { \
            int d = nt * 32 + l32; \
            int c = s * 2 + half; \
            short8 vf = *(const short8*)(Vc + d * 64 + ((c ^ (d & 7)) * 8)); \
            oacc[nt] = __builtin_amdgcn_mfma_f32_32x32x16_bf16(pf, vf, oacc[nt], 0, 0, 0); \
        } \
    } \
    __builtin_amdgcn_s_setprio(0); \
} while (0)

#define EPILOG(rs, oacc, qrow_w) do { \
    float tot = (rs) + __shfl_xor((rs), 32); \
    float inv = 1.0f / tot; \
    float invr[16]; \
    _Pragma("unroll") for (int e = 0; e < 16; e++) \
        invr[e] = __shfl(inv, (e & 3) + 8 * (e >> 2) + 4 * half); \
    _Pragma("unroll") for (int nt = 0; nt < 2; nt++) { \
        _Pragma("unroll") for (int e = 0; e < 16; e++) { \
            int r = (e & 3) + 8 * (e >> 2) + 4 * half; \
            int nn = (qrow_w) + r; \
            out[((size_t)b * 2048 + nn) * 1024 + h * 64 + nt * 32 + l32] = oacc[nt][e] * invr[e]; \
        } \
    } \
} while (0)

    int NT = 2 * qt + 2;            // 64-key tiles to process (2..32)
    int qrow = qt * 128 + wid * 32; // wave owns q-rows qrow..qrow+31
    int qlane = qrow + l32;

    short8 qf[4];
#pragma unroll
    for (int s = 0; s < 4; s++)
        qf[s] = *(const short8*)(qp + (size_t)qlane * 64 + s * 16 + half * 8);

    floatx16 oacc[2];
#pragma unroll
    for (int nt = 0; nt < 2; nt++)
#pragma unroll
        for (int e = 0; e < 16; e++) oacc[nt][e] = 0.f;
    float rs = 0.f;

    STAGE_KV(0, 0);

    for (int t = 0; t < NT; t++) {
        int kvb = t * 64;

        // WAR guard: all waves done reading slot (t+1)&1 (read at t-1)
        BARRIER();
        if (t + 1 < NT) {
            STAGE_KV((t + 1) & 1, kvb + 64);
            asm volatile("s_waitcnt vmcnt(4)" ::: "memory");  // S(t) (mine) done
        } else {
            asm volatile("s_waitcnt vmcnt(0)" ::: "memory");
        }
        BARRIER();   // RAW: S(t) visible to all waves

        const short* Kc = &Ks[t & 1][0];
        const short* Vc = &Vs[t & 1][0];

        bool d = (kvb + 63 > qrow);
        STREAM_TILE(qf, qlane, oacc, rs, d);
    }

    EPILOG(rs, oacc, qrow);

#undef STREAM_TILE
#undef EPILOG
#undef STAGE_KV
#undef BARRIER
}

extern "C" void kernel_launch(void* const* d_in, const int* in_sizes, int n_in,
                              void* d_out, int out_size, void* d_ws, size_t ws_size,
                              hipStream_t stream) {
    const float* x = (const float*)d_in[0];
    const float* Wq = (const float*)d_in[1];
    const float* Wk = (const float*)d_in[2];
    const float* Wv = (const float*)d_in[3];
    float* out = (float*)d_out;
    char* ws = (char*)d_ws;

    short* xb = (short*)ws;                          // 16 MB: [8192,1024] bf16
    short* wb = (short*)(ws + (16u << 20));          //  6 MB: [3,1024,1024] bf16
    short* qb = (short*)(ws + (22u << 20));          // 16 MB: [4,16,2048,64]
    short* kb = (short*)(ws + (38u << 20));          // 16 MB: [4,16,2048,64]
    short* vtb = (short*)(ws + (54u << 20));         // 16 MB: [4,16,64,2048]

    cast_all<<<8192 + 3 * 1024, 256, 0, stream>>>(x, Wq, Wk, Wv, xb, wb);
    qkv_gemm<<<dim3(64, 8, 3), 256, 0, stream>>>(xb, wb, qb, kb, vtb);
    attn<<<1024, 256, 0, stream>>>(qb, kb, vtb, out);
}